// Round 3
// baseline (1072.791 us; speedup 1.0000x reference)
//
#include <hip/hip_runtime.h>
#include <hip/hip_bf16.h>

#define NN 64
#define BATCH 512
#define SP 60
#define SG 180
#define SEX 10
#define CATD 80
#define NA 5
#define NR 7
#define OO 8
#define II 8

typedef unsigned long long u64;
typedef unsigned short u16;
typedef unsigned int u32;

// ---- workspace layout (float offsets) ----
#define OFF_Z     0
#define OFF_DZ    327680
#define OFF_HAS   655360
#define OFF_WIHF  688128
#define OFF_WHHF  698928
#define OFF_BIHF  709728
#define OFF_BHHF  709908
#define OFF_WIHB  710088
#define OFF_WHHB  720888
#define OFF_BIHB  731688
#define OFF_BHHB  731868
#define OFF_WF    732048
#define OFF_BF    736848
#define OFF_WB    736908
#define OFF_BB    741708
#define OFF_WA    741768
#define OFF_BA    742368
#define OFF_WC    742373
#define OFF_BC    742493
#define OFF_WU    742494
#define OFF_BU    743334
#define CONV_TOTAL 743341
#define OFF_RHOF  743344
#define OFF_RHOB  (OFF_RHOF + 1966080)
#define OFF_ALF   (OFF_RHOB + 1966080)
#define OFF_ALB   (OFF_ALF + 30720)
#define OFF_OSTG  (OFF_ALB + 30720)
#define OUT_TOTAL 232448

__device__ __forceinline__ float us2f(u16 v){
  return __uint_as_float(((u32)v) << 16);
}
__device__ __forceinline__ u16 f2bf(float f){
  __hip_bfloat16 h = __float2bfloat16(f);
  return *reinterpret_cast<u16*>(&h);
}
__device__ __forceinline__ float sigm(float x){ return 1.f/(1.f+__expf(-x)); }
__device__ __forceinline__ float tanh_(float x){
  float ax = fabsf(x);
  float e = __expf(-2.f*ax);
  float t = (1.f - e)/(1.f + e);
  return copysignf(t, x);
}

// has is exactly {0,1}. f32 words: only 0x00000000 / 0x3F800000.
// bf16-pair words: 0x3F803F80 == (1.0,1.0) appears w.p. ~0.81 per pair.
__device__ __forceinline__ int detect_bf16(const u32* w){
  int f = 0;
  for (int i=0;i<256;i++) f |= (w[i] == 0x3F803F80u) ? 1 : 0;
  return f;
}

__global__ __launch_bounds__(256) void conv_in(
  const void* z, const void* dz, const void* has,
  const void* WihF, const void* WhhF, const void* bihF, const void* bhhF,
  const void* WihB, const void* WhhB, const void* bihB, const void* bhhB,
  const void* Wf_, const void* bf_, const void* Wb_, const void* bb_,
  const void* Wa, const void* ba, const void* Wc, const void* bc,
  const void* Wu, const void* bu, float* ws)
{
  const int isbf = detect_bf16((const u32*)has);
  int idx = blockIdx.x*256 + threadIdx.x;
  if (idx >= CONV_TOTAL) return;
  const void* src; int loc;
  if      (idx < OFF_DZ  ){ src=z;    loc=idx-OFF_Z;    }
  else if (idx < OFF_HAS ){ src=dz;   loc=idx-OFF_DZ;   }
  else if (idx < OFF_WIHF){ src=has;  loc=idx-OFF_HAS;  }
  else if (idx < OFF_WHHF){ src=WihF; loc=idx-OFF_WIHF; }
  else if (idx < OFF_BIHF){ src=WhhF; loc=idx-OFF_WHHF; }
  else if (idx < OFF_BHHF){ src=bihF; loc=idx-OFF_BIHF; }
  else if (idx < OFF_WIHB){ src=bhhF; loc=idx-OFF_BHHF; }
  else if (idx < OFF_WHHB){ src=WihB; loc=idx-OFF_WIHB; }
  else if (idx < OFF_BIHB){ src=WhhB; loc=idx-OFF_WHHB; }
  else if (idx < OFF_BHHB){ src=bihB; loc=idx-OFF_BIHB; }
  else if (idx < OFF_WF  ){ src=bhhB; loc=idx-OFF_BHHB; }
  else if (idx < OFF_BF  ){ src=Wf_;  loc=idx-OFF_WF;   }
  else if (idx < OFF_WB  ){ src=bf_;  loc=idx-OFF_BF;   }
  else if (idx < OFF_BB  ){ src=Wb_;  loc=idx-OFF_WB;   }
  else if (idx < OFF_WA  ){ src=bb_;  loc=idx-OFF_BB;   }
  else if (idx < OFF_BA  ){ src=Wa;   loc=idx-OFF_WA;   }
  else if (idx < OFF_WC  ){ src=ba;   loc=idx-OFF_BA;   }
  else if (idx < OFF_BC  ){ src=Wc;   loc=idx-OFF_WC;   }
  else if (idx < OFF_WU  ){ src=bc;   loc=idx-OFF_BC;   }
  else if (idx < OFF_BU  ){ src=Wu;   loc=idx-OFF_WU;   }
  else                    { src=bu;   loc=idx-OFF_BU;   }
  float v = isbf ? us2f(((const u16*)src)[loc]) : ((const float*)src)[loc];
  ws[idx] = v;
}

__global__ __launch_bounds__(256) void conv_out(
  const void* has, const float* ws, void* out)
{
  const int isbf = detect_bf16((const u32*)has);
  int idx = blockIdx.x*256 + threadIdx.x;
  if (idx >= OUT_TOTAL) return;
  float v = ws[OFF_OSTG + idx];
  if (isbf) ((u16*)out)[idx] = f2bf(v);
  else      ((float*)out)[idx] = v;
}

// One block = 1 batch row of one direction. blocks 0..511 fwd, 512..1023 bwd.
// Thread t < 180 owns gate-row t (rows 0..59: r, 60..119: z, 120..179: n).
// Registers: Whh row (60 f32), Wih row (30 packed bf16), Wcat chunk (20 packed).
__global__ __launch_bounds__(192, 3) void dir_kernel(const int* __restrict__ adj,
                                                     float* __restrict__ ws)
{
  const int tid = threadIdx.x;
  const int bid = blockIdx.x;
  const int bwd = bid >> 9;
  const int b   = bid & 511;

  const float* Wih  = ws + (bwd ? OFF_WIHB : OFF_WIHF);
  const float* Whh  = ws + (bwd ? OFF_WHHB : OFF_WHHF);
  const float* bih  = ws + (bwd ? OFF_BIHB : OFF_BIHF);
  const float* bhh  = ws + (bwd ? OFF_BHHB : OFF_BHHF);
  const float* Wcat = ws + (bwd ? OFF_WB   : OFF_WF);
  const float* bcat = ws + (bwd ? OFF_BB   : OFF_BF);
  const float* zc   = ws + OFF_Z;     // [512][64][10]
  const float* dzc  = ws + OFF_DZ;
  const float* hasc = ws + OFF_HAS;   // [512][64]
  float* rho   = ws + (bwd ? OFF_RHOB : OFF_RHOF);  // [64][512][60]
  float* alpha = ws + (bwd ? OFF_ALB  : OFF_ALF);   // [512][60]

  __shared__ u16 sGi[NN][192];               // gi per node, bf16
  __shared__ __align__(16) float sH[2][64];  // h double buffer (60 used)
  __shared__ float sGh[192];
  __shared__ float sPart[3][64];
  __shared__ float sRhoCur[64];
  __shared__ float sHasRow[64];
  __shared__ float sZ[NN][SEX];
  __shared__ float sDZ[NN][SEX];
  __shared__ u64 sMask[NN];

  const int g = tid / 60;         // gate index 0/1/2 (3 for pad threads)
  const int n = tid - g*60;       // unit within gate

  // ---- staging ----
  if (tid < NN){
    u64 m = 0;
    if (!bwd){ for (int j=0;j<NN;j++) m |= ((u64)(adj[j*NN+tid]!=0))<<j; }  // preds of tid
    else     { for (int j=0;j<NN;j++) m |= ((u64)(adj[tid*NN+j]!=0))<<j; }  // succs of tid
    sMask[tid] = m;
    sHasRow[tid] = hasc[b*NN + tid];
    sH[0][tid] = 0.f; sH[1][tid] = 0.f;
  }
  for (int idx = tid; idx < NN*SEX; idx += 192){
    sZ [idx/SEX][idx%SEX] = zc [(size_t)b*NN*SEX + idx];
    sDZ[idx/SEX][idx%SEX] = dzc[(size_t)b*NN*SEX + idx];
  }

  float wh[60];          // Whh row t, f32
  u32   wihp[30];        // Wih row t, packed bf16 pairs
  u32   wcp[20];         // Wcat chunk, packed bf16 pairs
  float bih_t = 0.f, bhh_t = 0.f, bcat_t = 0.f;
  if (tid < SG){
    #pragma unroll
    for (int k=0;k<60;k++) wh[k] = Whh[tid*SP + k];
    #pragma unroll
    for (int k=0;k<30;k++){
      u16 lo = f2bf(Wih[tid*SP + 2*k]);
      u16 hi = f2bf(Wih[tid*SP + 2*k + 1]);
      wihp[k] = (u32)lo | ((u32)hi << 16);
    }
    bih_t = bih[tid]; bhh_t = bhh[tid];
    // Wcat chunk: g0 -> feat[0..19], g1 -> feat[20..39], g2 -> feat[40..79]
    const int start = n*CATD + ((g==2) ? 40 : g*20);
    #pragma unroll
    for (int k=0;k<20;k++){                 // g<2 uses only first 10 pairs
      u16 lo = f2bf(Wcat[start + 2*k]);
      u16 hi = f2bf(Wcat[start + 2*k + 1]);
      wcp[k] = (u32)lo | ((u32)hi << 16);
    }
  }
  if (tid < SP) bcat_t = bcat[tid];
  __syncthreads();

  int p = 0;
  float hreg = 0.f;

  auto edge_step = [&](int j){
    float gh0 = 0.f;
    if (tid < SG){
      float a0 = bhh_t, a1 = 0.f, a2 = 0.f, a3 = 0.f;
      const float4* h4 = (const float4*)&sH[p][0];
      #pragma unroll
      for (int q=0;q<15;q++){
        float4 hv = h4[q];
        a0 += hv.x * wh[4*q+0];
        a1 += hv.y * wh[4*q+1];
        a2 += hv.z * wh[4*q+2];
        a3 += hv.w * wh[4*q+3];
      }
      gh0 = (a0+a1)+(a2+a3);
      sGh[tid] = gh0;
    }
    __syncthreads();
    if (tid < SP){
      float gi0 = us2f(sGi[j][tid      ]);
      float gi1 = us2f(sGi[j][tid +  60]);
      float gi2 = us2f(sGi[j][tid + 120]);
      float gh1 = sGh[tid +  60];
      float gh2 = sGh[tid + 120];
      float r  = sigm(gi0 + gh0);
      float zg = sigm(gi1 + gh1);
      float nv = tanh_(gi2 + r*gh2);
      float hn = (1.f - zg)*nv + zg*hreg;
      float blend = sHasRow[j];               // exactly 0.0 or 1.0
      hreg = hreg + blend*(hn - hreg);
      sH[p^1][tid] = hreg;
    }
    __syncthreads();
    p ^= 1;
  };

  auto node_step = [&](int i){
    // phase 1: distributed rho partials over feat = [h(60); z_i(10); dz_i(10)]
    if (tid < SG){
      float part = 0.f;
      if (g < 2){
        const int k0 = g*20;
        #pragma unroll
        for (int kk=0;kk<10;kk++){
          u32 w2 = wcp[kk];
          part += __uint_as_float(w2 << 16)         * sH[p][k0 + 2*kk];
          part += __uint_as_float(w2 & 0xFFFF0000u) * sH[p][k0 + 2*kk + 1];
        }
      } else {
        #pragma unroll
        for (int kk=0;kk<10;kk++){
          u32 w2 = wcp[kk];
          part += __uint_as_float(w2 << 16)         * sH[p][40 + 2*kk];
          part += __uint_as_float(w2 & 0xFFFF0000u) * sH[p][40 + 2*kk + 1];
        }
        #pragma unroll
        for (int kk=10;kk<15;kk++){
          u32 w2 = wcp[kk];
          part += __uint_as_float(w2 << 16)         * sZ[i][2*(kk-10)];
          part += __uint_as_float(w2 & 0xFFFF0000u) * sZ[i][2*(kk-10)+1];
        }
        #pragma unroll
        for (int kk=15;kk<20;kk++){
          u32 w2 = wcp[kk];
          part += __uint_as_float(w2 << 16)         * sDZ[i][2*(kk-15)];
          part += __uint_as_float(w2 & 0xFFFF0000u) * sDZ[i][2*(kk-15)+1];
        }
      }
      sPart[g][n] = part;
    }
    __syncthreads();
    // phase 2: reduce -> rho_i, reset h
    if (tid < SP){
      float acc = bcat_t + sPart[0][tid] + sPart[1][tid] + sPart[2][tid];
      float rv = bwd ? acc : tanh_(acc);
      sRhoCur[tid] = rv;
      rho[((size_t)i*BATCH + b)*SP + tid] = rv;
      hreg = 0.f;
      sH[p^1][tid] = 0.f;
    }
    __syncthreads();
    // phase 3: gi_i = Wih @ rho_i + bih -> LDS (bf16)
    if (tid < SG){
      float a = bih_t;
      #pragma unroll
      for (int kk=0;kk<30;kk++){
        u32 w2 = wihp[kk];
        a += __uint_as_float(w2 << 16)         * sRhoCur[2*kk];
        a += __uint_as_float(w2 & 0xFFFF0000u) * sRhoCur[2*kk+1];
      }
      sGi[i][tid] = f2bf(a);
    }
    __syncthreads();
    p ^= 1;
  };

  if (!bwd){
    for (int i=0;i<NN;i++){
      u64 w = sMask[i];                       // strictly-upper adj: bits j<i only
      while (w){
        int j = (int)__builtin_ctzll(w);
        w &= (w-1);
        edge_step(j);                         // ascending j, matches reference scan
      }
      node_step(i);
    }
    for (int i=NN-OO;i<NN;i++) edge_step(i);  // alpha_f
  } else {
    for (int i=NN-1;i>=0;i--){
      u64 w = sMask[i];                       // bits j>i only
      while (w){
        int j = 63 - (int)__builtin_clzll(w);
        w &= ~(1ULL << j);
        edge_step(j);                         // descending j, matches reference scan
      }
      node_step(i);
    }
    for (int i=II-1;i>=0;i--) edge_step(i);   // alpha_b
  }
  if (tid < SP) alpha[(size_t)b*SP + tid] = hreg;
}

// One block per batch element: psi + softmaxes, omega, value -> f32 staging.
__global__ __launch_bounds__(256, 1) void head_kernel(float* __restrict__ ws)
{
  const int b = blockIdx.x;
  const int tid = threadIdx.x;
  const float* hasc   = ws + OFF_HAS;
  const float* WaC    = ws + OFF_WA;
  const float* baC    = ws + OFF_BA;
  const float* WcC    = ws + OFF_WC;
  const float* bcC    = ws + OFF_BC;
  const float* WuC    = ws + OFF_WU;
  const float* buC    = ws + OFF_BU;
  const float* rhoF   = ws + OFF_RHOF;
  const float* rhoB   = ws + OFF_RHOB;
  const float* alphaF = ws + OFF_ALF;
  const float* alphaB = ws + OFF_ALB;
  float* stg          = ws + OFF_OSTG;

  __shared__ float sF[NN][121];        // feats, padded (odd stride -> conflict-free)
  __shared__ float sAB[120];
  __shared__ float sWu[NR*120];
  __shared__ float sHasR[NN];
  __shared__ float sPsi[NR][NN];
  __shared__ float sRed[NR][2];
  __shared__ float sOm[NA];

  for (int idx=tid; idx<NN*SP; idx+=256){
    int n = idx/SP, s = idx%SP;
    sF[n][s]    = rhoF[((size_t)n*BATCH + b)*SP + s];
    sF[n][60+s] = rhoB[((size_t)n*BATCH + b)*SP + s];
  }
  for (int idx=tid; idx<120; idx+=256)
    sAB[idx] = (idx<60) ? alphaF[(size_t)b*SP + idx] : alphaB[(size_t)b*SP + idx-60];
  for (int idx=tid; idx<NR*120; idx+=256) sWu[idx] = WuC[idx];
  for (int idx=tid; idx<NN; idx+=256) sHasR[idx] = hasc[b*NN + idx];
  __syncthreads();

  for (int idx=tid; idx<NR*NN; idx+=256){
    int r = idx/NN, n = idx%NN;
    float acc = buC[r];
    for (int s=0;s<120;s++) acc += sF[n][s]*sWu[r*120+s];
    sPsi[r][n] = (sHasR[n] != 0.f) ? acc : -60.f;
  }
  if (tid >= 64 && tid < 64+NA){
    int a = tid - 64;
    float acc = baC[a];
    for (int s=0;s<120;s++) acc += sAB[s]*WaC[a*120+s];
    sOm[a] = acc;
  }
  if (tid == 70){
    float acc = bcC[0];
    for (int s=0;s<120;s++) acc += sAB[s]*WcC[s];
    stg[2560 + BATCH*NR*NN + b] = acc;                 // value
  }
  __syncthreads();

  if (tid < NR){
    float m = -1e30f;
    for (int n=0;n<NN;n++) m = fmaxf(m, sPsi[tid][n]);
    float ssum = 0.f;
    for (int n=0;n<NN;n++) ssum += __expf(sPsi[tid][n]-m);
    sRed[tid][0] = m; sRed[tid][1] = 1.f/ssum;
  }
  if (tid == 8){
    float m = -1e30f;
    for (int a=0;a<NA;a++) m = fmaxf(m, sOm[a]);
    float e[NA]; float ssum = 0.f;
    for (int a=0;a<NA;a++){ e[a] = __expf(sOm[a]-m); ssum += e[a]; }
    for (int a=0;a<NA;a++) stg[b*NA + a] = e[a]/ssum;  // instr_prob
  }
  __syncthreads();

  for (int idx=tid; idx<NR*NN; idx+=256){
    int r = idx/NN, n = idx%NN;
    float v = __expf(sPsi[r][n]-sRed[r][0]) * sRed[r][1];
    stg[2560 + (size_t)b*NR*NN + idx] = v;             // role_prob
  }
}

extern "C" void kernel_launch(void* const* d_in, const int* in_sizes, int n_in,
                              void* d_out, int out_size, void* d_ws, size_t ws_size,
                              hipStream_t stream)
{
  const int* adj = (const int*)d_in[3];
  float* ws = (float*)d_ws;

  conv_in<<<(CONV_TOTAL+255)/256, 256, 0, stream>>>(
      d_in[0], d_in[1], d_in[2],
      d_in[4], d_in[5], d_in[6], d_in[7],
      d_in[8], d_in[9], d_in[10], d_in[11],
      d_in[12], d_in[13], d_in[14], d_in[15],
      d_in[16], d_in[17], d_in[18], d_in[19],
      d_in[20], d_in[21], ws);

  dir_kernel<<<1024, 192, 0, stream>>>(adj, ws);

  head_kernel<<<512, 256, 0, stream>>>(ws);

  conv_out<<<(OUT_TOTAL+255)/256, 256, 0, stream>>>(d_in[2], ws, d_out);
}

// Round 4
// 437.578 us; speedup vs baseline: 2.4517x; 2.4517x over previous
//
#include <hip/hip_runtime.h>
#include <hip/hip_bf16.h>

#define NN 64
#define BATCH 512
#define SP 60
#define SG 180
#define SEX 10
#define CATD 80
#define NA 5
#define NR 7
#define OO 8
#define II 8

typedef unsigned long long u64;
typedef unsigned short u16;
typedef unsigned int u32;

// ---- workspace layout (float offsets) ----
#define OFF_Z     0
#define OFF_DZ    327680
#define OFF_HAS   655360
#define OFF_WIHF  688128
#define OFF_WHHF  698928
#define OFF_BIHF  709728
#define OFF_BHHF  709908
#define OFF_WIHB  710088
#define OFF_WHHB  720888
#define OFF_BIHB  731688
#define OFF_BHHB  731868
#define OFF_WF    732048
#define OFF_BF    736848
#define OFF_WB    736908
#define OFF_BB    741708
#define OFF_WA    741768
#define OFF_BA    742368
#define OFF_WC    742373
#define OFF_BC    742493
#define OFF_WU    742494
#define OFF_BU    743334
#define CONV_TOTAL 743341
#define OFF_RHOF  743344
#define OFF_RHOB  (OFF_RHOF + 1966080)
#define OFF_ALF   (OFF_RHOB + 1966080)
#define OFF_ALB   (OFF_ALF + 30720)
#define OFF_OSTG  (OFF_ALB + 30720)
#define OUT_TOTAL 232448

typedef _Float16 f16;
typedef _Float16 half2_t __attribute__((ext_vector_type(2)));

__device__ __forceinline__ float us2f(u16 v){
  return __uint_as_float(((u32)v) << 16);
}
__device__ __forceinline__ u16 f2bf(float f){
  __hip_bfloat16 h = __float2bfloat16(f);
  return *reinterpret_cast<u16*>(&h);
}
__device__ __forceinline__ float sigm(float x){ return 1.f/(1.f+__expf(-x)); }
__device__ __forceinline__ float tanh_(float x){
  float ax = fabsf(x);
  float e = __expf(-2.f*ax);
  float t = (1.f - e)/(1.f + e);
  return copysignf(t, x);
}
__device__ __forceinline__ u32 pack2(float a, float b){
  half2_t h; h[0] = (f16)a; h[1] = (f16)b;
  return __builtin_bit_cast(u32, h);
}
__device__ __forceinline__ float fdot2_(u32 a, u32 b, float c){
  return __builtin_amdgcn_fdot2(__builtin_bit_cast(half2_t, a),
                                __builtin_bit_cast(half2_t, b), c, false);
}

struct HP { uint4 q[8]; };
__device__ __forceinline__ u32 hpc(const HP& p, int k){
  const uint4& v = p.q[k>>2];
  switch(k&3){ case 0: return v.x; case 1: return v.y; case 2: return v.z; default: return v.w; }
}

#define LOAD_HP(P, I) do { const uint4* _r=(const uint4*)&sH4[I][0]; \
  _Pragma("unroll") for(int _k=0;_k<8;_k++) (P).q[_k]=_r[_k]; } while(0)

#define OWNH(I) ((float)*(const f16*)((const char*)&sH4[I][0] + 2*u))

#define GATE_DOTS(WR, WZ, WN, P, AR, AZ, AN) do { \
  float _r0=0.f,_r1=0.f,_z0=0.f,_z1=0.f,_n0=0.f,_n1=0.f; \
  _Pragma("unroll") \
  for (int k=0;k<30;k+=2){ \
    u32 _h0 = hpc(P,k), _h1 = hpc(P,k+1); \
    _r0=fdot2_(WR[k],_h0,_r0); _r1=fdot2_(WR[k+1],_h1,_r1); \
    _z0=fdot2_(WZ[k],_h0,_z0); _z1=fdot2_(WZ[k+1],_h1,_z1); \
    _n0=fdot2_(WN[k],_h0,_n0); _n1=fdot2_(WN[k+1],_h1,_n1); \
  } \
  AR=_r0+_r1; AZ=_z0+_z1; AN=_n0+_n1; \
} while(0)

// has is exactly {0,1}. f32 words: only 0x00000000 / 0x3F800000.
__device__ __forceinline__ int detect_bf16(const u32* w){
  int f = 0;
  for (int i=0;i<256;i++) f |= (w[i] == 0x3F803F80u) ? 1 : 0;
  return f;
}

__global__ __launch_bounds__(256) void conv_in(
  const void* z, const void* dz, const void* has,
  const void* WihF, const void* WhhF, const void* bihF, const void* bhhF,
  const void* WihB, const void* WhhB, const void* bihB, const void* bhhB,
  const void* Wf_, const void* bf_, const void* Wb_, const void* bb_,
  const void* Wa, const void* ba, const void* Wc, const void* bc,
  const void* Wu, const void* bu, float* ws)
{
  const int isbf = detect_bf16((const u32*)has);
  int idx = blockIdx.x*256 + threadIdx.x;
  if (idx >= CONV_TOTAL) return;
  const void* src; int loc;
  if      (idx < OFF_DZ  ){ src=z;    loc=idx-OFF_Z;    }
  else if (idx < OFF_HAS ){ src=dz;   loc=idx-OFF_DZ;   }
  else if (idx < OFF_WIHF){ src=has;  loc=idx-OFF_HAS;  }
  else if (idx < OFF_WHHF){ src=WihF; loc=idx-OFF_WIHF; }
  else if (idx < OFF_BIHF){ src=WhhF; loc=idx-OFF_WHHF; }
  else if (idx < OFF_BHHF){ src=bihF; loc=idx-OFF_BIHF; }
  else if (idx < OFF_WIHB){ src=bhhF; loc=idx-OFF_BHHF; }
  else if (idx < OFF_WHHB){ src=WihB; loc=idx-OFF_WIHB; }
  else if (idx < OFF_BIHB){ src=WhhB; loc=idx-OFF_WHHB; }
  else if (idx < OFF_BHHB){ src=bihB; loc=idx-OFF_BIHB; }
  else if (idx < OFF_WF  ){ src=bhhB; loc=idx-OFF_BHHB; }
  else if (idx < OFF_BF  ){ src=Wf_;  loc=idx-OFF_WF;   }
  else if (idx < OFF_WB  ){ src=bf_;  loc=idx-OFF_BF;   }
  else if (idx < OFF_BB  ){ src=Wb_;  loc=idx-OFF_WB;   }
  else if (idx < OFF_WA  ){ src=bb_;  loc=idx-OFF_BB;   }
  else if (idx < OFF_BA  ){ src=Wa;   loc=idx-OFF_WA;   }
  else if (idx < OFF_WC  ){ src=ba;   loc=idx-OFF_BA;   }
  else if (idx < OFF_BC  ){ src=Wc;   loc=idx-OFF_WC;   }
  else if (idx < OFF_WU  ){ src=bc;   loc=idx-OFF_BC;   }
  else if (idx < OFF_BU  ){ src=Wu;   loc=idx-OFF_WU;   }
  else                    { src=bu;   loc=idx-OFF_BU;   }
  float v = isbf ? us2f(((const u16*)src)[loc]) : ((const float*)src)[loc];
  ws[idx] = v;
}

__global__ __launch_bounds__(256) void conv_out(
  const void* has, const float* ws, void* out)
{
  const int isbf = detect_bf16((const u32*)has);
  int idx = blockIdx.x*256 + threadIdx.x;
  if (idx >= OUT_TOTAL) return;
  float v = ws[OFF_OSTG + idx];
  if (isbf) ((u16*)out)[idx] = f2bf(v);
  else      ((float*)out)[idx] = v;
}

// Pipelined DAG-GRU: one wave (64 threads) per (batch row, direction).
// Lane u owns hidden unit u; Whh/Wih rows u,u+60,u+120 + Wcat row u live in
// VGPRs as packed f16 pairs (bf16->f16 is exact). 64 outer steps: at step t,
// rho_t and gi_t are computed once, then all consumers i of edge (t,i) get
// their h_i advanced in parallel (order across steps matches the reference
// scan order; consumers within a step touch disjoint h rows).
__global__ __launch_bounds__(64, 1) void dir_kernel(const int* __restrict__ adj,
                                                    float* __restrict__ ws)
{
  const int u   = threadIdx.x;      // hidden unit (active < 60)
  const int bid = blockIdx.x;
  const int bwd = bid >> 9;
  const int b   = bid & 511;

  const float* Wih  = ws + (bwd ? OFF_WIHB : OFF_WIHF);
  const float* Whh  = ws + (bwd ? OFF_WHHB : OFF_WHHF);
  const float* bih  = ws + (bwd ? OFF_BIHB : OFF_BIHF);
  const float* bhh  = ws + (bwd ? OFF_BHHB : OFF_BHHF);
  const float* Wcat = ws + (bwd ? OFF_WB   : OFF_WF);
  const float* bcat = ws + (bwd ? OFF_BB   : OFF_BF);
  const float* zc   = ws + OFF_Z;
  const float* dzc  = ws + OFF_DZ;
  const float* hasc = ws + OFF_HAS;
  float* rho   = ws + (bwd ? OFF_RHOB : OFF_RHOF);  // [64][512][60]
  float* alpha = ws + (bwd ? OFF_ALB  : OFF_ALF);   // [512][60]

  __shared__ uint4 sH4[65][8];        // h[node][60] as f16 pairs; row 64 = tail scratch
  __shared__ uint4 sRho4[8];          // current rho as f16 pairs
  __shared__ u32 sZp[NN][5];
  __shared__ u32 sDZp[NN][5];
  __shared__ float sHas[NN];
  __shared__ float sGiT[8][3][64];    // gi for tail nodes (f32)
  __shared__ u64 sRowM[NN];
  __shared__ u64 sColM[NN];

  // ---- staging ----
  {
    u64 rowm = 0;
    for (int j=0;j<64;j++) rowm |= ((u64)(adj[u*64+j]!=0))<<j;
    sRowM[u] = rowm;
    sHas[u] = hasc[b*NN + u];
    for (int idx=u; idx<65*8; idx+=64) ((uint4*)sH4)[idx] = uint4{0,0,0,0};
    for (int idx=u; idx<NN*5; idx+=64){
      int n2=idx/5, p2=idx%5;
      sZp [n2][p2] = pack2(zc [(size_t)b*NN*SEX + n2*SEX + 2*p2],
                           zc [(size_t)b*NN*SEX + n2*SEX + 2*p2+1]);
      sDZp[n2][p2] = pack2(dzc[(size_t)b*NN*SEX + n2*SEX + 2*p2],
                           dzc[(size_t)b*NN*SEX + n2*SEX + 2*p2+1]);
    }
  }
  __syncthreads();
  {
    u64 colm = 0;
    for (int i2=0;i2<64;i2++) colm |= ((sRowM[i2]>>u)&1ULL)<<i2;
    sColM[u] = colm;
  }

  // per-lane weights (packed f16 pairs) — all-lane loads, OOB rows land in
  // adjacent ws regions (finite, unused by lanes >= 60)
  u32 whr[30], whz[30], whn[30], wir[30], wiz[30], win[30], wc[40];
  #pragma unroll
  for (int k=0;k<30;k++){
    whr[k] = pack2(Whh[(u     )*SP + 2*k], Whh[(u     )*SP + 2*k+1]);
    whz[k] = pack2(Whh[(u+ 60 )*SP + 2*k], Whh[(u+ 60 )*SP + 2*k+1]);
    whn[k] = pack2(Whh[(u+120 )*SP + 2*k], Whh[(u+120 )*SP + 2*k+1]);
    wir[k] = pack2(Wih[(u     )*SP + 2*k], Wih[(u     )*SP + 2*k+1]);
    wiz[k] = pack2(Wih[(u+ 60 )*SP + 2*k], Wih[(u+ 60 )*SP + 2*k+1]);
    win[k] = pack2(Wih[(u+120 )*SP + 2*k], Wih[(u+120 )*SP + 2*k+1]);
  }
  #pragma unroll
  for (int k=0;k<40;k++) wc[k] = pack2(Wcat[u*CATD + 2*k], Wcat[u*CATD + 2*k+1]);
  const float bhr = bhh[u], bhz = bhh[u+60], bhn = bhh[u+120];
  const float bir = bih[u], biz = bih[u+60], bin_ = bih[u+120];
  const float bct = bcat[u];
  __syncthreads();

  // ---- 64 pipelined steps ----
  int t = bwd ? 63 : 0;
  const int dt = bwd ? -1 : 1;
  for (int s=0; s<64; s++, t+=dt){
    // phase 1: rho_t from h_t (+z_t, dz_t)
    {
      HP ht; LOAD_HP(ht, t);
      float c0 = bct, c1 = 0.f;
      #pragma unroll
      for (int k=0;k<30;k+=2){
        c0 = fdot2_(wc[k],   hpc(ht,k),   c0);
        c1 = fdot2_(wc[k+1], hpc(ht,k+1), c1);
      }
      #pragma unroll
      for (int p2=0;p2<5;p2++){
        c0 = fdot2_(wc[30+p2], sZp [t][p2], c0);
        c1 = fdot2_(wc[35+p2], sDZp[t][p2], c1);
      }
      float acc = c0 + c1;
      float rv = bwd ? acc : tanh_(acc);
      if (u < SP){
        rho[((size_t)t*BATCH + b)*SP + u] = rv;
        *(f16*)((char*)&sRho4[0] + 2*u) = (f16)rv;
      }
    }
    __syncthreads();
    // phase 2: gi_t = Wih @ rho_t + bih (3 values, in-lane)
    float gr, gz, gn;
    {
      HP rp; LOAD_HP(rp, 0);  // reuse loader shape via explicit pointer below
      // (sRho4 is a different array; load manually)
      const uint4* _r = (const uint4*)&sRho4[0];
      #pragma unroll
      for (int _k=0;_k<8;_k++) rp.q[_k] = _r[_k];
      GATE_DOTS(wir, wiz, win, rp, gr, gz, gn);
      gr += bir; gz += biz; gn += bin_;
    }
    const int slot = bwd ? t : (t - (NN-OO));
    if (slot >= 0 && slot < 8){
      sGiT[slot][0][u] = gr; sGiT[slot][1][u] = gz; sGiT[slot][2][u] = gn;
    }
    // phase 3: advance all consumers of step t (uniform skip if has[b,t]==0)
    const float blendT = sHas[t];
    u64 m = bwd ? sColM[t] : sRowM[t];
    if (m && blendT != 0.f){
      int i = (int)__builtin_ctzll(m); m &= m-1;
      HP A; LOAD_HP(A, i);
      float holdA = OWNH(i);
      for (;;){
        int j = -1; HP B; float holdB = 0.f;
        if (m){ j = (int)__builtin_ctzll(m); m &= m-1;
                LOAD_HP(B, j); holdB = OWNH(j); }
        {
          float ar,az,an; GATE_DOTS(whr,whz,whn,A,ar,az,an);
          ar+=bhr; az+=bhz; an+=bhn;
          float r_=sigm(gr+ar), zg_=sigm(gz+az), nv_=tanh_(gn+r_*an);
          float hn_=(1.f-zg_)*nv_+zg_*holdA;
          float hw_=holdA+blendT*(hn_-holdA);
          if (u<SP) *(f16*)((char*)&sH4[i][0]+2*u) = (f16)hw_;
        }
        if (j < 0) break;
        int k2 = -1;
        if (m){ k2 = (int)__builtin_ctzll(m); m &= m-1;
                LOAD_HP(A, k2); holdA = OWNH(k2); }
        {
          float ar,az,an; GATE_DOTS(whr,whz,whn,B,ar,az,an);
          ar+=bhr; az+=bhz; an+=bhn;
          float r_=sigm(gr+ar), zg_=sigm(gz+az), nv_=tanh_(gn+r_*an);
          float hn_=(1.f-zg_)*nv_+zg_*holdB;
          float hw_=holdB+blendT*(hn_-holdB);
          if (u<SP) *(f16*)((char*)&sH4[j][0]+2*u) = (f16)hw_;
        }
        if (k2 < 0) break;
        i = k2;
      }
    }
    __syncthreads();
  }

  // ---- alpha tail: 8 plain GRU steps on scratch row 64 (zeroed at init) ----
  float hA = 0.f;
  for (int s2=0; s2<8; s2++){
    const int i = bwd ? (7 - s2) : (NN - OO + s2);
    const int slot = bwd ? i : (i - (NN-OO));
    HP P; LOAD_HP(P, 64);
    float ar,az,an; GATE_DOTS(whr,whz,whn,P,ar,az,an);
    ar+=bhr; az+=bhz; an+=bhn;
    float gr2=sGiT[slot][0][u], gz2=sGiT[slot][1][u], gn2=sGiT[slot][2][u];
    float r_=sigm(gr2+ar), zg_=sigm(gz2+az), nv_=tanh_(gn2+r_*an);
    float hn_=(1.f-zg_)*nv_+zg_*hA;
    float blend = sHas[i];
    hA = hA + blend*(hn_-hA);
    __syncthreads();
    if (u<SP) *(f16*)((char*)&sH4[64][0]+2*u) = (f16)hA;
    __syncthreads();
  }
  if (u<SP) alpha[(size_t)b*SP + u] = hA;
}

// One block per batch element: psi + softmaxes, omega, value -> f32 staging.
__global__ __launch_bounds__(256, 1) void head_kernel(float* __restrict__ ws)
{
  const int b = blockIdx.x;
  const int tid = threadIdx.x;
  const float* hasc   = ws + OFF_HAS;
  const float* WaC    = ws + OFF_WA;
  const float* baC    = ws + OFF_BA;
  const float* WcC    = ws + OFF_WC;
  const float* bcC    = ws + OFF_BC;
  const float* WuC    = ws + OFF_WU;
  const float* buC    = ws + OFF_BU;
  const float* rhoF   = ws + OFF_RHOF;
  const float* rhoB   = ws + OFF_RHOB;
  const float* alphaF = ws + OFF_ALF;
  const float* alphaB = ws + OFF_ALB;
  float* stg          = ws + OFF_OSTG;

  __shared__ float sF[NN][121];
  __shared__ float sAB[120];
  __shared__ float sWu[NR*120];
  __shared__ float sHasR[NN];
  __shared__ float sPsi[NR][NN];
  __shared__ float sRed[NR][2];
  __shared__ float sOm[NA];

  for (int idx=tid; idx<NN*SP; idx+=256){
    int n = idx/SP, s = idx%SP;
    sF[n][s]    = rhoF[((size_t)n*BATCH + b)*SP + s];
    sF[n][60+s] = rhoB[((size_t)n*BATCH + b)*SP + s];
  }
  for (int idx=tid; idx<120; idx+=256)
    sAB[idx] = (idx<60) ? alphaF[(size_t)b*SP + idx] : alphaB[(size_t)b*SP + idx-60];
  for (int idx=tid; idx<NR*120; idx+=256) sWu[idx] = WuC[idx];
  for (int idx=tid; idx<NN; idx+=256) sHasR[idx] = hasc[b*NN + idx];
  __syncthreads();

  for (int idx=tid; idx<NR*NN; idx+=256){
    int r = idx/NN, n = idx%NN;
    float acc = buC[r];
    for (int s=0;s<120;s++) acc += sF[n][s]*sWu[r*120+s];
    sPsi[r][n] = (sHasR[n] != 0.f) ? acc : -60.f;
  }
  if (tid >= 64 && tid < 64+NA){
    int a = tid - 64;
    float acc = baC[a];
    for (int s=0;s<120;s++) acc += sAB[s]*WaC[a*120+s];
    sOm[a] = acc;
  }
  if (tid == 70){
    float acc = bcC[0];
    for (int s=0;s<120;s++) acc += sAB[s]*WcC[s];
    stg[2560 + BATCH*NR*NN + b] = acc;                 // value
  }
  __syncthreads();

  if (tid < NR){
    float m = -1e30f;
    for (int n=0;n<NN;n++) m = fmaxf(m, sPsi[tid][n]);
    float ssum = 0.f;
    for (int n=0;n<NN;n++) ssum += __expf(sPsi[tid][n]-m);
    sRed[tid][0] = m; sRed[tid][1] = 1.f/ssum;
  }
  if (tid == 8){
    float m = -1e30f;
    for (int a=0;a<NA;a++) m = fmaxf(m, sOm[a]);
    float e[NA]; float ssum = 0.f;
    for (int a=0;a<NA;a++){ e[a] = __expf(sOm[a]-m); ssum += e[a]; }
    for (int a=0;a<NA;a++) stg[b*NA + a] = e[a]/ssum;  // instr_prob
  }
  __syncthreads();

  for (int idx=tid; idx<NR*NN; idx+=256){
    int r = idx/NN, n = idx%NN;
    float v = __expf(sPsi[r][n]-sRed[r][0]) * sRed[r][1];
    stg[2560 + (size_t)b*NR*NN + idx] = v;             // role_prob
  }
}

extern "C" void kernel_launch(void* const* d_in, const int* in_sizes, int n_in,
                              void* d_out, int out_size, void* d_ws, size_t ws_size,
                              hipStream_t stream)
{
  const int* adj = (const int*)d_in[3];
  float* ws = (float*)d_ws;

  conv_in<<<(CONV_TOTAL+255)/256, 256, 0, stream>>>(
      d_in[0], d_in[1], d_in[2],
      d_in[4], d_in[5], d_in[6], d_in[7],
      d_in[8], d_in[9], d_in[10], d_in[11],
      d_in[12], d_in[13], d_in[14], d_in[15],
      d_in[16], d_in[17], d_in[18], d_in[19],
      d_in[20], d_in[21], ws);

  dir_kernel<<<1024, 64, 0, stream>>>(adj, ws);

  head_kernel<<<512, 256, 0, stream>>>(ws);

  conv_out<<<(OUT_TOTAL+255)/256, 256, 0, stream>>>(d_in[2], ws, d_out);
}